// Round 1
// baseline (1061.038 us; speedup 1.0000x reference)
//
#include <hip/hip_runtime.h>

// ---------------- constants ----------------
#define T_LEN 2048
#define DM    768
#define DI    1536
#define DS    16
#define BB    2
#define NROWS (BB * T_LEN)   // 4096
#define NCH   64             // scan chunks per sequence
#define CLEN  32             // chunk length (NCH*CLEN == T_LEN)

// param-buffer (f32) segment offsets (elements)
#define OFF_DTB 0
#define OFF_A   6144
#define OFF_DP  104448
#define OFF_CW  110592
#define OFF_CB  135168
#define OFF_LG  141312
#define OFF_LB  144384
#define PRM_TOT 147456

typedef __attribute__((ext_vector_type(8))) short bh8;
typedef __attribute__((ext_vector_type(4))) float f32x4;

// ---------------- small helpers ----------------
__device__ __forceinline__ float bf2f(unsigned short u) {
    return __uint_as_float(((unsigned)u) << 16);
}
__device__ __forceinline__ unsigned short f2bf(float f) {
    unsigned u = __float_as_uint(f);
    u += 0x7FFFu + ((u >> 16) & 1u);   // RNE
    return (unsigned short)(u >> 16);
}
__device__ __forceinline__ float ldin(const void* p, long i, int bf) {
    return bf ? bf2f(((const unsigned short*)p)[i]) : ((const float*)p)[i];
}

// ---------------- dtype sniffer ----------------
// bf16 data: ~all uint16 have sane exponent; f32 data: low halves are mantissa junk.
__global__ void k_sniff(const unsigned short* __restrict__ x, int* __restrict__ flag) {
    __shared__ int cnt[4];
    int tid = threadIdx.x;
    int local = 0;
#pragma unroll
    for (int j = 0; j < 4; ++j) {
        unsigned short u = x[tid * 4 + j];
        int e = (u >> 7) & 0xFF;
        if (e >= 100 && e <= 140) local++;
    }
    for (int off = 32; off; off >>= 1) local += __shfl_down(local, off, 64);
    if ((tid & 63) == 0) cnt[tid >> 6] = local;
    __syncthreads();
    if (tid == 0) {
        int tot = cnt[0] + cnt[1] + cnt[2] + cnt[3];
        *flag = (tot >= 900) ? 1 : 0;
    }
}

// ---------------- conversions ----------------
__global__ void k_conv_bf16(unsigned short* __restrict__ dst, const void* __restrict__ src,
                            long n, const int* __restrict__ flag) {
    int bf = *flag;
    long i = (long)blockIdx.x * 256 + threadIdx.x;
    if (i < n) dst[i] = bf ? ((const unsigned short*)src)[i] : f2bf(((const float*)src)[i]);
}

__global__ void k_convx(unsigned short* __restrict__ xbf, float* __restrict__ xf,
                        const void* __restrict__ src, const int* __restrict__ flag) {
    int bf = *flag;
    long i = (long)blockIdx.x * 256 + threadIdx.x;
    if (i < (long)NROWS * DM) {
        float v = ldin(src, i, bf);
        xbf[i] = f2bf(v);
        xf[i]  = v;
    }
}

// x_proj_w [4][80][1536] -> bf16 [4][128][1536], rows 80..127 zero
__global__ void k_conv_xpw(unsigned short* __restrict__ dst, const void* __restrict__ src,
                           const int* __restrict__ flag) {
    int bf = *flag;
    long i = (long)blockIdx.x * 256 + threadIdx.x;
    const long total = 4L * 128 * 1536;
    if (i < total) {
        int c = (int)(i % 1536);
        long rl = i / 1536;
        int r = (int)(rl % 128);
        int l = (int)(rl / 128);
        unsigned short v = 0;
        if (r < 80) {
            long si = ((long)l * 80 + r) * 1536 + c;
            v = bf ? ((const unsigned short*)src)[si] : f2bf(((const float*)src)[si]);
        }
        dst[i] = v;
    }
}

// dt_proj_w [4][1536][48] -> bf16 [4][1536][64], cols 48..63 zero
__global__ void k_conv_dtw(unsigned short* __restrict__ dst, const void* __restrict__ src,
                           const int* __restrict__ flag) {
    int bf = *flag;
    long i = (long)blockIdx.x * 256 + threadIdx.x;
    const long total = 4L * 1536 * 64;
    if (i < total) {
        int c = (int)(i % 64);
        long rl = i / 64;
        int d = (int)(rl % 1536);
        int l = (int)(rl / 1536);
        unsigned short v = 0;
        if (c < 48) {
            long si = ((long)l * 1536 + d) * 48 + c;
            v = bf ? ((const unsigned short*)src)[si] : f2bf(((const float*)src)[si]);
        }
        dst[i] = v;
    }
}

// small params -> one f32 buffer (A transformed to -exp(A_log))
__global__ void k_params(float* __restrict__ prm, const void* dtb, const void* alog,
                         const void* dpar, const void* cw, const void* cb,
                         const void* lg, const void* lb, const int* __restrict__ flag) {
    int bf = *flag;
    int i = blockIdx.x * 256 + threadIdx.x;
    if (i >= PRM_TOT) return;
    float v;
    if (i < OFF_A)        v = ldin(dtb, i - OFF_DTB, bf);
    else if (i < OFF_DP)  v = -__expf(ldin(alog, i - OFF_A, bf));
    else if (i < OFF_CW)  v = ldin(dpar, i - OFF_DP, bf);
    else if (i < OFF_CB)  v = ldin(cw, i - OFF_CW, bf);
    else if (i < OFF_LG)  v = ldin(cb, i - OFF_CB, bf);
    else if (i < OFF_LB)  v = ldin(lg, i - OFF_LG, bf);
    else                  v = ldin(lb, i - OFF_LB, bf);
    prm[i] = v;
}

// ---------------- GEMM: C[M,N] = A[M,K] @ B[N,K]^T  (bf16 in, f32 out) ----------------
// 128x128 tile, BK=32, 256 threads = 4 waves in 2x2, each wave 64x64 (4x4 MFMA tiles)
template <int EPI>
__global__ __launch_bounds__(256) void k_gemm128(const unsigned short* __restrict__ A,
                                                 const unsigned short* __restrict__ B,
                                                 float* __restrict__ C,
                                                 int M, int N, int K) {
    __shared__ __align__(16) unsigned short As[128 * 32];
    __shared__ __align__(16) unsigned short Bs[128 * 32];
    const int tid = threadIdx.x;
    const int lane = tid & 63, wid = tid >> 6;
    const int wm = wid >> 1, wn = wid & 1;
    const long arow0 = (long)blockIdx.y * 128;
    const long bcol0 = (long)blockIdx.x * 128;
    f32x4 acc[4][4] = {};

    for (int k0 = 0; k0 < K; k0 += 32) {
#pragma unroll
        for (int j = 0; j < 2; ++j) {
            int g = (j * 256 + tid) * 8;
            int r = g >> 5, c = g & 31;
            *(int4*)&As[g] = *(const int4*)&A[(arow0 + r) * K + k0 + c];
            *(int4*)&Bs[g] = *(const int4*)&B[(bcol0 + r) * K + k0 + c];
        }
        __syncthreads();
        const int row = lane & 15, q8 = (lane >> 4) * 8;
        bh8 af[4], bfr[4];
#pragma unroll
        for (int i = 0; i < 4; ++i) af[i] = *(const bh8*)&As[(wm * 64 + i * 16 + row) * 32 + q8];
#pragma unroll
        for (int i = 0; i < 4; ++i) bfr[i] = *(const bh8*)&Bs[(wn * 64 + i * 16 + row) * 32 + q8];
#pragma unroll
        for (int i = 0; i < 4; ++i)
#pragma unroll
            for (int j = 0; j < 4; ++j)
                acc[i][j] = __builtin_amdgcn_mfma_f32_16x16x32_bf16(af[i], bfr[j], acc[i][j], 0, 0, 0);
        __syncthreads();
    }
    const int crow = (lane >> 4) * 4, ccol = lane & 15;
#pragma unroll
    for (int i = 0; i < 4; ++i)
#pragma unroll
        for (int j = 0; j < 4; ++j)
#pragma unroll
            for (int r = 0; r < 4; ++r) {
                long gr = arow0 + wm * 64 + i * 16 + crow + r;
                long gc = bcol0 + wn * 64 + j * 16 + ccol;
                C[gr * N + gc] = acc[i][j][r];
            }
}

// 64x64 tile variant; EPI: 0 plain, 1 bias+softplus (dt_proj), 2 also emit padded bf16 dtlr (x_proj)
template <int EPI>
__global__ __launch_bounds__(256) void k_gemm64(const unsigned short* __restrict__ A,
                                                const unsigned short* __restrict__ B,
                                                float* __restrict__ C,
                                                int M, int N, int K,
                                                const float* __restrict__ bias,
                                                unsigned short* __restrict__ dtlr) {
    __shared__ __align__(16) unsigned short As[64 * 32];
    __shared__ __align__(16) unsigned short Bs[64 * 32];
    const int tid = threadIdx.x;
    const int lane = tid & 63, wid = tid >> 6;
    const int wm = wid >> 1, wn = wid & 1;
    const long arow0 = (long)blockIdx.y * 64;
    const long bcol0 = (long)blockIdx.x * 64;
    f32x4 acc[2][2] = {};

    for (int k0 = 0; k0 < K; k0 += 32) {
        int g = tid * 8;
        int r = g >> 5, c = g & 31;
        *(int4*)&As[g] = *(const int4*)&A[(arow0 + r) * K + k0 + c];
        *(int4*)&Bs[g] = *(const int4*)&B[(bcol0 + r) * K + k0 + c];
        __syncthreads();
        const int row = lane & 15, q8 = (lane >> 4) * 8;
        bh8 af[2], bfr[2];
#pragma unroll
        for (int i = 0; i < 2; ++i) af[i] = *(const bh8*)&As[(wm * 32 + i * 16 + row) * 32 + q8];
#pragma unroll
        for (int i = 0; i < 2; ++i) bfr[i] = *(const bh8*)&Bs[(wn * 32 + i * 16 + row) * 32 + q8];
#pragma unroll
        for (int i = 0; i < 2; ++i)
#pragma unroll
            for (int j = 0; j < 2; ++j)
                acc[i][j] = __builtin_amdgcn_mfma_f32_16x16x32_bf16(af[i], bfr[j], acc[i][j], 0, 0, 0);
        __syncthreads();
    }
    const int crow = (lane >> 4) * 4, ccol = lane & 15;
#pragma unroll
    for (int i = 0; i < 2; ++i)
#pragma unroll
        for (int j = 0; j < 2; ++j)
#pragma unroll
            for (int r = 0; r < 4; ++r) {
                long gr = arow0 + wm * 32 + i * 16 + crow + r;
                long gc = bcol0 + wn * 32 + j * 16 + ccol;
                float v = acc[i][j][r];
                if (EPI == 1) {
                    v += bias[gc];
                    v = (v > 20.f) ? v : log1pf(__expf(v));
                }
                C[gr * N + gc] = v;
                if (EPI == 2) {
                    if (gc < 64) dtlr[gr * 64 + gc] = (gc < 48) ? f2bf(v) : (unsigned short)0;
                }
            }
}

// ---------------- depthwise causal conv + SiLU ----------------
__global__ __launch_bounds__(256) void k_conv(const float* __restrict__ xz,
                                              const float* __restrict__ cw,
                                              const float* __restrict__ cb,
                                              float* __restrict__ xc,
                                              unsigned short* __restrict__ xcbf) {
    long i = (long)blockIdx.x * 256 + threadIdx.x;
    if (i >= (long)NROWS * DI) return;
    int d = (int)(i % DI);
    long bt = i / DI;
    int t = (int)(bt & (T_LEN - 1));
    float acc = cb[d];
#pragma unroll
    for (int k = 0; k < 4; ++k) {
        int ts = t + k - 3;
        if (ts >= 0) acc += xz[(bt + k - 3) * (2 * DI) + d] * cw[d * 4 + k];
    }
    float s = acc / (1.f + __expf(-acc));   // SiLU
    xc[i] = s;
    xcbf[i] = f2bf(s);
}

// ---------------- chunked selective scan ----------------
// phase 1: per (b,chunk,d): local scan from h=0; store final h and P[n]=exp(A_n * sum(dt))
__global__ __launch_bounds__(256) void k_scan1(const float* __restrict__ dt,
                                               const float* __restrict__ xc,
                                               const float* __restrict__ dbl,
                                               const float* __restrict__ An,
                                               float* __restrict__ hch,
                                               float* __restrict__ ppr) {
    __shared__ float BsL[CLEN * DS];
    const int tid = threadIdx.x;
    const int db = blockIdx.x % 6;
    const int c  = (blockIdx.x / 6) % NCH;
    const int b  = blockIdx.x / (6 * NCH);
    const int d  = db * 256 + tid;
    const int t0 = c * CLEN;
    for (int j = tid; j < CLEN * DS; j += 256) {
        int tt = j >> 4, nn = j & 15;
        BsL[j] = dbl[((long)b * T_LEN + t0 + tt) * 128 + 48 + nn];
    }
    __syncthreads();
    float h[DS], An_r[DS];
#pragma unroll
    for (int n = 0; n < DS; ++n) { h[n] = 0.f; An_r[n] = An[d * DS + n]; }
    float sdt = 0.f;
    for (int s = 0; s < CLEN; ++s) {
        long bt = (long)b * T_LEN + t0 + s;
        float dtv = dt[bt * DI + d];
        float xcv = xc[bt * DI + d];
        float du = dtv * xcv;
        sdt += dtv;
#pragma unroll
        for (int n = 0; n < DS; ++n) {
            float a = __expf(An_r[n] * dtv);
            h[n] = a * h[n] + du * BsL[s * DS + n];
        }
    }
    long o = (((long)b * NCH + c) * DI + d) * DS;
#pragma unroll
    for (int n = 0; n < DS; ++n) {
        hch[o + n] = h[n];
        ppr[o + n] = __expf(An_r[n] * sdt);
    }
}

// phase 2: sequential combine over chunks per (b,d,n)
__global__ __launch_bounds__(256) void k_scan2(const float* __restrict__ hch,
                                               const float* __restrict__ ppr,
                                               float* __restrict__ hin) {
    long gid = (long)blockIdx.x * 256 + threadIdx.x;
    if (gid >= (long)BB * DI * DS) return;
    int n = (int)(gid & 15);
    long r = gid >> 4;
    int d = (int)(r % DI);
    int b = (int)(r / DI);
    float h = 0.f;
    for (int c = 0; c < NCH; ++c) {
        long idx = (((long)b * NCH + c) * DI + d) * DS + n;
        hin[idx] = h;
        h = ppr[idx] * h + hch[idx];
    }
}

// phase 3: re-scan with carried-in h; fuse y = (scan + xc*D) * silu(z); emit bf16
__global__ __launch_bounds__(256) void k_scan3(const float* __restrict__ dt,
                                               const float* __restrict__ xc,
                                               const float* __restrict__ dbl,
                                               const float* __restrict__ An,
                                               const float* __restrict__ Dp,
                                               const float* __restrict__ hin,
                                               const float* __restrict__ xz,
                                               unsigned short* __restrict__ ybf) {
    __shared__ float BsL[CLEN * DS];
    __shared__ float CsL[CLEN * DS];
    const int tid = threadIdx.x;
    const int db = blockIdx.x % 6;
    const int c  = (blockIdx.x / 6) % NCH;
    const int b  = blockIdx.x / (6 * NCH);
    const int d  = db * 256 + tid;
    const int t0 = c * CLEN;
    for (int j = tid; j < CLEN * DS; j += 256) {
        int tt = j >> 4, nn = j & 15;
        long base = ((long)b * T_LEN + t0 + tt) * 128;
        BsL[j] = dbl[base + 48 + nn];
        CsL[j] = dbl[base + 64 + nn];
    }
    __syncthreads();
    float h[DS], An_r[DS];
    long o = (((long)b * NCH + c) * DI + d) * DS;
#pragma unroll
    for (int n = 0; n < DS; ++n) { h[n] = hin[o + n]; An_r[n] = An[d * DS + n]; }
    const float dcoef = Dp[d];
    for (int s = 0; s < CLEN; ++s) {
        long bt = (long)b * T_LEN + t0 + s;
        float dtv = dt[bt * DI + d];
        float xcv = xc[bt * DI + d];
        float du = dtv * xcv;
        float y = 0.f;
#pragma unroll
        for (int n = 0; n < DS; ++n) {
            float a = __expf(An_r[n] * dtv);
            h[n] = a * h[n] + du * BsL[s * DS + n];
            y += h[n] * CsL[s * DS + n];
        }
        y += xcv * dcoef;
        float zv = xz[bt * (2 * DI) + DI + d];
        y *= zv / (1.f + __expf(-zv));      // * silu(z)
        ybf[bt * DI + d] = f2bf(y);
    }
}

// ---------------- LayerNorm + residual (+ final output store) ----------------
__global__ __launch_bounds__(256) void k_ln(const float* __restrict__ prj,
                                            float* __restrict__ x,
                                            unsigned short* __restrict__ xbf,
                                            const float* __restrict__ lg,
                                            const float* __restrict__ lb,
                                            void* __restrict__ dout,
                                            int is_last, const int* __restrict__ flag) {
    __shared__ float red[8];
    const int row = blockIdx.x;
    const int tid = threadIdx.x;
    float v[3];
    float s = 0.f, s2 = 0.f;
#pragma unroll
    for (int j = 0; j < 3; ++j) {
        v[j] = prj[(long)row * DM + tid + j * 256];
        s += v[j];
        s2 += v[j] * v[j];
    }
    for (int off = 32; off; off >>= 1) {
        s  += __shfl_down(s, off, 64);
        s2 += __shfl_down(s2, off, 64);
    }
    if ((tid & 63) == 0) { red[tid >> 6] = s; red[4 + (tid >> 6)] = s2; }
    __syncthreads();
    float S  = red[0] + red[1] + red[2] + red[3];
    float S2 = red[4] + red[5] + red[6] + red[7];
    float mu = S * (1.f / DM);
    float var = S2 * (1.f / DM) - mu * mu;
    float rs = rsqrtf(var + 1e-5f);
    int bf = *flag;
#pragma unroll
    for (int j = 0; j < 3; ++j) {
        int e = tid + j * 256;
        long idx = (long)row * DM + e;
        float out = (v[j] - mu) * rs * lg[e] + lb[e] + x[idx];
        x[idx] = out;
        xbf[idx] = f2bf(out);
        if (is_last) {
            if (bf) ((unsigned short*)dout)[idx] = f2bf(out);
            else    ((float*)dout)[idx] = out;
        }
    }
}

// ---------------- host launcher ----------------
extern "C" void kernel_launch(void* const* d_in, const int* in_sizes, int n_in,
                              void* d_out, int out_size, void* d_ws, size_t ws_size,
                              hipStream_t stream) {
    char* ws = (char*)d_ws;
    // workspace offsets (bytes)
    const size_t O_FLAG = 0;
    const size_t O_WIN  = 256;                     // in_proj_w bf16: 4*3072*768
    const size_t O_WXP  = O_WIN + 18874368;        // x_proj_w padded bf16: 4*128*1536
    const size_t O_WDT  = O_WXP + 1572864;         // dt_proj_w padded bf16: 4*1536*64
    const size_t O_WOUT = O_WDT + 786432;          // out_proj_w bf16: 4*768*1536
    const size_t O_PRM  = O_WOUT + 9437184;        // small params f32
    const size_t O_XBF  = O_PRM + 589824;          // x bf16 [4096,768]
    const size_t O_XF   = O_XBF + 6291456;         // x f32
    const size_t O_XZ   = O_XF + 12582912;         // xz f32 [4096,3072] (also aliases prj)
    const size_t O_XC   = O_XZ + 50331648;         // xc f32 [4096,1536]
    const size_t O_XCBF = O_XC + 25165824;         // xc bf16
    const size_t O_DBL  = O_XCBF + 12582912;       // dbl f32 [4096,128]
    const size_t O_DTLR = O_DBL + 2097152;         // dt lowrank bf16 [4096,64]
    const size_t O_DT   = O_DTLR + 524288;         // dt f32 [4096,1536]
    const size_t O_HCH  = O_DT + 25165824;         // chunk h [2,64,1536,16]
    const size_t O_PPR  = O_HCH + 12582912;        // chunk prod
    const size_t O_HIN  = O_PPR + 12582912;        // chunk incoming h
    const size_t O_YBF  = O_HIN + 12582912;        // y bf16 [4096,1536]

    int* flag = (int*)(ws + O_FLAG);
    unsigned short* Win  = (unsigned short*)(ws + O_WIN);
    unsigned short* Wxp  = (unsigned short*)(ws + O_WXP);
    unsigned short* Wdt  = (unsigned short*)(ws + O_WDT);
    unsigned short* Wout = (unsigned short*)(ws + O_WOUT);
    float* prm = (float*)(ws + O_PRM);
    unsigned short* Xbf = (unsigned short*)(ws + O_XBF);
    float* Xf  = (float*)(ws + O_XF);
    float* Xz  = (float*)(ws + O_XZ);
    float* Xc  = (float*)(ws + O_XC);
    unsigned short* Xcbf = (unsigned short*)(ws + O_XCBF);
    float* Dbl = (float*)(ws + O_DBL);
    unsigned short* Dtlr = (unsigned short*)(ws + O_DTLR);
    float* Dt  = (float*)(ws + O_DT);
    float* Hch = (float*)(ws + O_HCH);
    float* Ppr = (float*)(ws + O_PPR);
    float* Hin = (float*)(ws + O_HIN);
    unsigned short* Ybf = (unsigned short*)(ws + O_YBF);
    float* Prj = Xz;   // alias: out_proj result reuses xz region (z consumed by then)

    const void* in_x   = d_in[0];
    const void* in_inw = d_in[1];
    const void* in_cw  = d_in[2];
    const void* in_cb  = d_in[3];
    const void* in_xpw = d_in[4];
    const void* in_dtw = d_in[5];
    const void* in_dtb = d_in[6];
    const void* in_al  = d_in[7];
    const void* in_dp  = d_in[8];
    const void* in_ow  = d_in[9];
    const void* in_lg  = d_in[10];
    const void* in_lb  = d_in[11];

    // dtype sniff + conversions
    k_sniff<<<1, 256, 0, stream>>>((const unsigned short*)in_x, flag);
    k_convx<<<12288, 256, 0, stream>>>(Xbf, Xf, in_x, flag);
    k_conv_bf16<<<36864, 256, 0, stream>>>(Win, in_inw, 9437184L, flag);
    k_conv_bf16<<<18432, 256, 0, stream>>>(Wout, in_ow, 4718592L, flag);
    k_conv_xpw<<<3072, 256, 0, stream>>>(Wxp, in_xpw, flag);
    k_conv_dtw<<<1536, 256, 0, stream>>>(Wdt, in_dtw, flag);
    k_params<<<576, 256, 0, stream>>>(prm, in_dtb, in_al, in_dp, in_cw, in_cb, in_lg, in_lb, flag);

    for (int l = 0; l < 4; ++l) {
        const unsigned short* winL  = Win  + (size_t)l * 3072 * 768;
        const unsigned short* wxpL  = Wxp  + (size_t)l * 128 * 1536;
        const unsigned short* wdtL  = Wdt  + (size_t)l * 1536 * 64;
        const unsigned short* woutL = Wout + (size_t)l * 768 * 1536;
        const float* cwL  = prm + OFF_CW  + (size_t)l * DI * 4;
        const float* cbL  = prm + OFF_CB  + (size_t)l * DI;
        const float* dtbL = prm + OFF_DTB + (size_t)l * DI;
        const float* anL  = prm + OFF_A   + (size_t)l * DI * DS;
        const float* dpL  = prm + OFF_DP  + (size_t)l * DI;
        const float* lgL  = prm + OFF_LG  + (size_t)l * DM;
        const float* lbL  = prm + OFF_LB  + (size_t)l * DM;

        // in_proj: [4096,768] x [3072,768]^T -> xz [4096,3072]
        k_gemm128<0><<<dim3(24, 32), 256, 0, stream>>>(Xbf, winL, Xz, NROWS, 2 * DI, DM);
        // conv + silu
        k_conv<<<24576, 256, 0, stream>>>(Xz, cwL, cbL, Xc, Xcbf);
        // x_proj: [4096,1536] x [128,1536]^T -> dbl [4096,128]; also emit dtlr bf16
        k_gemm64<2><<<dim3(2, 64), 256, 0, stream>>>(Xcbf, wxpL, Dbl, NROWS, 128, DI, nullptr, Dtlr);
        // dt_proj: [4096,64] x [1536,64]^T + bias -> softplus -> dt [4096,1536]
        k_gemm64<1><<<dim3(24, 64), 256, 0, stream>>>(Dtlr, wdtL, Dt, NROWS, DI, 64, dtbL, nullptr);
        // chunked scan
        k_scan1<<<768, 256, 0, stream>>>(Dt, Xc, Dbl, anL, Hch, Ppr);
        k_scan2<<<192, 256, 0, stream>>>(Hch, Ppr, Hin);
        k_scan3<<<768, 256, 0, stream>>>(Dt, Xc, Dbl, anL, dpL, Hin, Xz, Ybf);
        // out_proj: [4096,1536] x [768,1536]^T -> prj [4096,768]
        k_gemm64<0><<<dim3(12, 64), 256, 0, stream>>>(Ybf, woutL, Prj, NROWS, DM, DI, nullptr, nullptr);
        // layernorm + residual (+ final store on last layer)
        k_ln<<<4096, 256, 0, stream>>>(Prj, Xf, Xbf, lgL, lbL, d_out, (l == 3) ? 1 : 0, flag);
    }
}

// Round 2
// 1020.753 us; speedup vs baseline: 1.0395x; 1.0395x over previous
//
#include <hip/hip_runtime.h>

// ---------------- constants ----------------
#define T_LEN 2048
#define DM    768
#define DI    1536
#define DS    16
#define BB    2
#define NROWS (BB * T_LEN)   // 4096
#define NCH   128            // scan chunks per sequence
#define CLEN  16             // chunk length (NCH*CLEN == T_LEN)

// param-buffer (f32) segment offsets (elements)
#define OFF_DTB 0
#define OFF_A   6144
#define OFF_DP  104448
#define OFF_CW  110592
#define OFF_CB  135168
#define OFF_LG  141312
#define OFF_LB  144384
#define PRM_TOT 147456

typedef __attribute__((ext_vector_type(8))) short bh8;
typedef __attribute__((ext_vector_type(4))) float f32x4;

typedef const __attribute__((address_space(1))) void as1_void;
typedef __attribute__((address_space(3))) void as3_void;

__device__ __forceinline__ void glds16(const void* g, void* l) {
    __builtin_amdgcn_global_load_lds((as1_void*)g, (as3_void*)l, 16, 0, 0);
}

// ---------------- small helpers ----------------
__device__ __forceinline__ float bf2f(unsigned short u) {
    return __uint_as_float(((unsigned)u) << 16);
}
__device__ __forceinline__ unsigned short f2bf(float f) {
    unsigned u = __float_as_uint(f);
    u += 0x7FFFu + ((u >> 16) & 1u);   // RNE
    return (unsigned short)(u >> 16);
}
__device__ __forceinline__ float ldin(const void* p, long i, int bf) {
    return bf ? bf2f(((const unsigned short*)p)[i]) : ((const float*)p)[i];
}

// ---------------- dtype sniffer ----------------
__global__ void k_sniff(const unsigned short* __restrict__ x, int* __restrict__ flag) {
    __shared__ int cnt[4];
    int tid = threadIdx.x;
    int local = 0;
#pragma unroll
    for (int j = 0; j < 4; ++j) {
        unsigned short u = x[tid * 4 + j];
        int e = (u >> 7) & 0xFF;
        if (e >= 100 && e <= 140) local++;
    }
    for (int off = 32; off; off >>= 1) local += __shfl_down(local, off, 64);
    if ((tid & 63) == 0) cnt[tid >> 6] = local;
    __syncthreads();
    if (tid == 0) {
        int tot = cnt[0] + cnt[1] + cnt[2] + cnt[3];
        *flag = (tot >= 900) ? 1 : 0;
    }
}

// ---------------- conversions ----------------
__global__ void k_conv_bf16(unsigned short* __restrict__ dst, const void* __restrict__ src,
                            long n, const int* __restrict__ flag) {
    int bf = *flag;
    long i = (long)blockIdx.x * 256 + threadIdx.x;
    if (i < n) dst[i] = bf ? ((const unsigned short*)src)[i] : f2bf(((const float*)src)[i]);
}

__global__ void k_convx(unsigned short* __restrict__ xbf, float* __restrict__ xf,
                        const void* __restrict__ src, const int* __restrict__ flag) {
    int bf = *flag;
    long i = (long)blockIdx.x * 256 + threadIdx.x;
    if (i < (long)NROWS * DM) {
        float v = ldin(src, i, bf);
        xbf[i] = f2bf(v);
        xf[i]  = v;
    }
}

// x_proj_w [4][80][1536] -> bf16 [4][128][1536], rows 80..127 zero
__global__ void k_conv_xpw(unsigned short* __restrict__ dst, const void* __restrict__ src,
                           const int* __restrict__ flag) {
    int bf = *flag;
    long i = (long)blockIdx.x * 256 + threadIdx.x;
    const long total = 4L * 128 * 1536;
    if (i < total) {
        int c = (int)(i % 1536);
        long rl = i / 1536;
        int r = (int)(rl % 128);
        int l = (int)(rl / 128);
        unsigned short v = 0;
        if (r < 80) {
            long si = ((long)l * 80 + r) * 1536 + c;
            v = bf ? ((const unsigned short*)src)[si] : f2bf(((const float*)src)[si]);
        }
        dst[i] = v;
    }
}

// dt_proj_w [4][1536][48] -> bf16 [4][1536][64], cols 48..63 zero
__global__ void k_conv_dtw(unsigned short* __restrict__ dst, const void* __restrict__ src,
                           const int* __restrict__ flag) {
    int bf = *flag;
    long i = (long)blockIdx.x * 256 + threadIdx.x;
    const long total = 4L * 1536 * 64;
    if (i < total) {
        int c = (int)(i % 64);
        long rl = i / 64;
        int d = (int)(rl % 1536);
        int l = (int)(rl / 1536);
        unsigned short v = 0;
        if (c < 48) {
            long si = ((long)l * 1536 + d) * 48 + c;
            v = bf ? ((const unsigned short*)src)[si] : f2bf(((const float*)src)[si]);
        }
        dst[i] = v;
    }
}

// small params -> one f32 buffer (A transformed to -exp(A_log))
__global__ void k_params(float* __restrict__ prm, const void* dtb, const void* alog,
                         const void* dpar, const void* cw, const void* cb,
                         const void* lg, const void* lb, const int* __restrict__ flag) {
    int bf = *flag;
    int i = blockIdx.x * 256 + threadIdx.x;
    if (i >= PRM_TOT) return;
    float v;
    if (i < OFF_A)        v = ldin(dtb, i - OFF_DTB, bf);
    else if (i < OFF_DP)  v = -__expf(ldin(alog, i - OFF_A, bf));
    else if (i < OFF_CW)  v = ldin(dpar, i - OFF_DP, bf);
    else if (i < OFF_CB)  v = ldin(cw, i - OFF_CW, bf);
    else if (i < OFF_LG)  v = ldin(cb, i - OFF_CB, bf);
    else if (i < OFF_LB)  v = ldin(lg, i - OFF_LG, bf);
    else                  v = ldin(lb, i - OFF_LB, bf);
    prm[i] = v;
}

// ---------------- GEMM: C[M,N] = A[M,K] @ B[N,K]^T  (bf16 in, f32 out) ----------------
// 128x128 tile, BK=32, global_load_lds width-16 staging (m97 pattern)
__global__ __launch_bounds__(256) void k_gemm128(const unsigned short* __restrict__ A,
                                                 const unsigned short* __restrict__ B,
                                                 float* __restrict__ C,
                                                 int M, int N, int K) {
    __shared__ __align__(16) unsigned short As[128 * 32];
    __shared__ __align__(16) unsigned short Bs[128 * 32];
    const int tid = threadIdx.x;
    const int lane = tid & 63, wid = tid >> 6;
    const int wm = wid >> 1, wn = wid & 1;
    const long arow0 = (long)blockIdx.y * 128;
    const long bcol0 = (long)blockIdx.x * 128;
    const int r16 = lane >> 2;            // 0..15
    const int c8  = (lane & 3) * 8;       // 0,8,16,24
    f32x4 acc[4][4] = {};

    for (int k0 = 0; k0 < K; k0 += 32) {
#pragma unroll
        for (int j = 0; j < 2; ++j) {
            int chunk = wid + j * 4;      // 0..7
            int row = chunk * 16 + r16;
            glds16(&A[(arow0 + row) * K + k0 + c8], &As[chunk * 512]);
            glds16(&B[(bcol0 + row) * K + k0 + c8], &Bs[chunk * 512]);
        }
        __syncthreads();
        const int row = lane & 15, q8 = (lane >> 4) * 8;
        bh8 af[4], bfr[4];
#pragma unroll
        for (int i = 0; i < 4; ++i) af[i] = *(const bh8*)&As[(wm * 64 + i * 16 + row) * 32 + q8];
#pragma unroll
        for (int i = 0; i < 4; ++i) bfr[i] = *(const bh8*)&Bs[(wn * 64 + i * 16 + row) * 32 + q8];
#pragma unroll
        for (int i = 0; i < 4; ++i)
#pragma unroll
            for (int j = 0; j < 4; ++j)
                acc[i][j] = __builtin_amdgcn_mfma_f32_16x16x32_bf16(af[i], bfr[j], acc[i][j], 0, 0, 0);
        __syncthreads();
    }
    const int crow = (lane >> 4) * 4, ccol = lane & 15;
#pragma unroll
    for (int i = 0; i < 4; ++i)
#pragma unroll
        for (int j = 0; j < 4; ++j)
#pragma unroll
            for (int r = 0; r < 4; ++r) {
                long gr = arow0 + wm * 64 + i * 16 + crow + r;
                long gc = bcol0 + wn * 64 + j * 16 + ccol;
                C[gr * N + gc] = acc[i][j][r];
            }
}

// 64x64 tile; EPI: 0 plain, 1 bias+softplus (dt_proj), 2 emit padded bf16 dtlr (x_proj)
template <int EPI>
__global__ __launch_bounds__(256) void k_gemm64(const unsigned short* __restrict__ A,
                                                const unsigned short* __restrict__ B,
                                                float* __restrict__ C,
                                                int M, int N, int K,
                                                const float* __restrict__ bias,
                                                unsigned short* __restrict__ dtlr) {
    __shared__ __align__(16) unsigned short As[64 * 32];
    __shared__ __align__(16) unsigned short Bs[64 * 32];
    const int tid = threadIdx.x;
    const int lane = tid & 63, wid = tid >> 6;
    const int wm = wid >> 1, wn = wid & 1;
    const long arow0 = (long)blockIdx.y * 64;
    const long bcol0 = (long)blockIdx.x * 64;
    const int r16 = lane >> 2;
    const int c8  = (lane & 3) * 8;
    f32x4 acc[2][2] = {};

    for (int k0 = 0; k0 < K; k0 += 32) {
        int row = wid * 16 + r16;
        glds16(&A[(arow0 + row) * K + k0 + c8], &As[wid * 512]);
        glds16(&B[(bcol0 + row) * K + k0 + c8], &Bs[wid * 512]);
        __syncthreads();
        const int row2 = lane & 15, q8 = (lane >> 4) * 8;
        bh8 af[2], bfr[2];
#pragma unroll
        for (int i = 0; i < 2; ++i) af[i] = *(const bh8*)&As[(wm * 32 + i * 16 + row2) * 32 + q8];
#pragma unroll
        for (int i = 0; i < 2; ++i) bfr[i] = *(const bh8*)&Bs[(wn * 32 + i * 16 + row2) * 32 + q8];
#pragma unroll
        for (int i = 0; i < 2; ++i)
#pragma unroll
            for (int j = 0; j < 2; ++j)
                acc[i][j] = __builtin_amdgcn_mfma_f32_16x16x32_bf16(af[i], bfr[j], acc[i][j], 0, 0, 0);
        __syncthreads();
    }
    const int crow = (lane >> 4) * 4, ccol = lane & 15;
#pragma unroll
    for (int i = 0; i < 2; ++i)
#pragma unroll
        for (int j = 0; j < 2; ++j)
#pragma unroll
            for (int r = 0; r < 4; ++r) {
                long gr = arow0 + wm * 32 + i * 16 + crow + r;
                long gc = bcol0 + wn * 32 + j * 16 + ccol;
                float v = acc[i][j][r];
                if (EPI == 1) {
                    v += bias[gc];
                    v = (v > 20.f) ? v : log1pf(__expf(v));
                }
                C[gr * N + gc] = v;
                if (EPI == 2) {
                    if (gc < 64) dtlr[gr * 64 + gc] = (gc < 48) ? f2bf(v) : (unsigned short)0;
                }
            }
}

// ---------------- depthwise causal conv + SiLU (emits bf16 only) ----------------
__global__ __launch_bounds__(256) void k_conv(const float* __restrict__ xz,
                                              const float* __restrict__ cw,
                                              const float* __restrict__ cb,
                                              unsigned short* __restrict__ xcbf) {
    long i = (long)blockIdx.x * 256 + threadIdx.x;
    if (i >= (long)NROWS * DI) return;
    int d = (int)(i % DI);
    long bt = i / DI;
    int t = (int)(bt & (T_LEN - 1));
    float acc = cb[d];
#pragma unroll
    for (int k = 0; k < 4; ++k) {
        int ts = t + k - 3;
        if (ts >= 0) acc += xz[(bt + k - 3) * (2 * DI) + d] * cw[d * 4 + k];
    }
    float s = acc / (1.f + __expf(-acc));   // SiLU
    xcbf[i] = f2bf(s);
}

// ---------------- chunked selective scan ----------------
// phase 1: per (b,chunk,d): local scan from h=0; store final h and sum(dt)
__global__ __launch_bounds__(256) void k_scan1(const float* __restrict__ dt,
                                               const unsigned short* __restrict__ xcbf,
                                               const float* __restrict__ dbl,
                                               const float* __restrict__ An,
                                               float* __restrict__ hch,
                                               float* __restrict__ sdtb) {
    const int tid = threadIdx.x;
    const int db = blockIdx.x % 6;
    const int c  = (blockIdx.x / 6) % NCH;
    const int b  = blockIdx.x / (6 * NCH);
    const int d  = db * 256 + tid;
    const int t0 = c * CLEN;
    float h[DS], An_r[DS];
    const f32x4* Ap = (const f32x4*)(An + (long)d * DS);
#pragma unroll
    for (int q = 0; q < 4; ++q) {
        f32x4 a4 = Ap[q];
#pragma unroll
        for (int j = 0; j < 4; ++j) { An_r[q * 4 + j] = a4[j]; h[q * 4 + j] = 0.f; }
    }
    float sdt = 0.f;
    const long rowb = (long)b * T_LEN + t0;
#pragma unroll 4
    for (int s = 0; s < CLEN; ++s) {
        long bt = rowb + s;
        float dtv = dt[bt * DI + d];
        float xcv = bf2f(xcbf[bt * DI + d]);
        int bi = __builtin_amdgcn_readfirstlane((int)(bt * 128 + 48));
        const f32x4* bp = (const f32x4*)(dbl + bi);
        float Bv[DS];
#pragma unroll
        for (int q = 0; q < 4; ++q) {
            f32x4 b4 = bp[q];
#pragma unroll
            for (int j = 0; j < 4; ++j) Bv[q * 4 + j] = b4[j];
        }
        float du = dtv * xcv;
        sdt += dtv;
#pragma unroll
        for (int n = 0; n < DS; ++n)
            h[n] = __expf(An_r[n] * dtv) * h[n] + du * Bv[n];
    }
    long o = (((long)b * NCH + c) * DI + d) * DS;
    f32x4* hp = (f32x4*)(hch + o);
#pragma unroll
    for (int q = 0; q < 4; ++q) {
        f32x4 h4;
#pragma unroll
        for (int j = 0; j < 4; ++j) h4[j] = h[q * 4 + j];
        hp[q] = h4;
    }
    sdtb[((long)b * NCH + c) * DI + d] = sdt;
}

// phase 2: sequential combine over chunks per (b,d,n).
// hbuf on entry = per-chunk local h; on exit = incoming (prefix) h per chunk.
__global__ __launch_bounds__(256) void k_scan2(float* __restrict__ hbuf,
                                               const float* __restrict__ sdtb,
                                               const float* __restrict__ An) {
    long gid = (long)blockIdx.x * 256 + threadIdx.x;
    if (gid >= (long)BB * DI * DS) return;
    int n = (int)(gid & 15);
    long r = gid >> 4;
    int d = (int)(r % DI);
    int b = (int)(r / DI);
    float an = An[(long)d * DS + n];
    float h = 0.f;
    for (int c = 0; c < NCH; ++c) {
        long idx = (((long)b * NCH + c) * DI + d) * DS + n;
        float p = __expf(an * sdtb[((long)b * NCH + c) * DI + d]);
        float g = hbuf[idx];
        hbuf[idx] = h;
        h = p * h + g;
    }
}

// phase 3: re-scan with carried-in h; fuse y = (scan + xc*D) * silu(z); emit bf16
__global__ __launch_bounds__(256) void k_scan3(const float* __restrict__ dt,
                                               const unsigned short* __restrict__ xcbf,
                                               const float* __restrict__ dbl,
                                               const float* __restrict__ An,
                                               const float* __restrict__ Dp,
                                               const float* __restrict__ hin,
                                               const float* __restrict__ xz,
                                               unsigned short* __restrict__ ybf) {
    const int tid = threadIdx.x;
    const int db = blockIdx.x % 6;
    const int c  = (blockIdx.x / 6) % NCH;
    const int b  = blockIdx.x / (6 * NCH);
    const int d  = db * 256 + tid;
    const int t0 = c * CLEN;
    float h[DS], An_r[DS];
    long o = (((long)b * NCH + c) * DI + d) * DS;
    const f32x4* Ap = (const f32x4*)(An + (long)d * DS);
    const f32x4* Hp = (const f32x4*)(hin + o);
#pragma unroll
    for (int q = 0; q < 4; ++q) {
        f32x4 a4 = Ap[q], h4 = Hp[q];
#pragma unroll
        for (int j = 0; j < 4; ++j) { An_r[q * 4 + j] = a4[j]; h[q * 4 + j] = h4[j]; }
    }
    const float dcoef = Dp[d];
    const long rowb = (long)b * T_LEN + t0;
#pragma unroll 4
    for (int s = 0; s < CLEN; ++s) {
        long bt = rowb + s;
        float dtv = dt[bt * DI + d];
        float xcv = bf2f(xcbf[bt * DI + d]);
        int bi = __builtin_amdgcn_readfirstlane((int)(bt * 128 + 48));
        const f32x4* bp = (const f32x4*)(dbl + bi);
        float Bv[DS], Cv[DS];
#pragma unroll
        for (int q = 0; q < 4; ++q) {
            f32x4 b4 = bp[q], c4 = bp[q + 4];
#pragma unroll
            for (int j = 0; j < 4; ++j) { Bv[q * 4 + j] = b4[j]; Cv[q * 4 + j] = c4[j]; }
        }
        float du = dtv * xcv;
        float yp[4] = {xcv * dcoef, 0.f, 0.f, 0.f};
#pragma unroll
        for (int n = 0; n < DS; ++n) {
            h[n] = __expf(An_r[n] * dtv) * h[n] + du * Bv[n];
            yp[n & 3] += h[n] * Cv[n];
        }
        float y = (yp[0] + yp[1]) + (yp[2] + yp[3]);
        float zv = xz[bt * (2 * DI) + DI + d];
        y *= zv / (1.f + __expf(-zv));      // * silu(z)
        ybf[bt * DI + d] = f2bf(y);
    }
}

// ---------------- LayerNorm + residual (+ final output store) ----------------
__global__ __launch_bounds__(256) void k_ln(const float* __restrict__ prj,
                                            float* __restrict__ x,
                                            unsigned short* __restrict__ xbf,
                                            const float* __restrict__ lg,
                                            const float* __restrict__ lb,
                                            void* __restrict__ dout,
                                            int is_last, const int* __restrict__ flag) {
    __shared__ float red[8];
    const int row = blockIdx.x;
    const int tid = threadIdx.x;
    float v[3];
    float s = 0.f, s2 = 0.f;
#pragma unroll
    for (int j = 0; j < 3; ++j) {
        v[j] = prj[(long)row * DM + tid + j * 256];
        s += v[j];
        s2 += v[j] * v[j];
    }
    for (int off = 32; off; off >>= 1) {
        s  += __shfl_down(s, off, 64);
        s2 += __shfl_down(s2, off, 64);
    }
    if ((tid & 63) == 0) { red[tid >> 6] = s; red[4 + (tid >> 6)] = s2; }
    __syncthreads();
    float S  = red[0] + red[1] + red[2] + red[3];
    float S2 = red[4] + red[5] + red[6] + red[7];
    float mu = S * (1.f / DM);
    float var = S2 * (1.f / DM) - mu * mu;
    float rs = rsqrtf(var + 1e-5f);
    int bf = *flag;
#pragma unroll
    for (int j = 0; j < 3; ++j) {
        int e = tid + j * 256;
        long idx = (long)row * DM + e;
        float out = (v[j] - mu) * rs * lg[e] + lb[e] + x[idx];
        x[idx] = out;
        xbf[idx] = f2bf(out);
        if (is_last) {
            if (bf) ((unsigned short*)dout)[idx] = f2bf(out);
            else    ((float*)dout)[idx] = out;
        }
    }
}

// ---------------- host launcher ----------------
extern "C" void kernel_launch(void* const* d_in, const int* in_sizes, int n_in,
                              void* d_out, int out_size, void* d_ws, size_t ws_size,
                              hipStream_t stream) {
    char* ws = (char*)d_ws;
    const size_t O_FLAG = 0;
    const size_t O_WIN  = 256;                     // 18,874,368
    const size_t O_WXP  = O_WIN + 18874368;        // 1,572,864
    const size_t O_WDT  = O_WXP + 1572864;         // 786,432
    const size_t O_WOUT = O_WDT + 786432;          // 9,437,184
    const size_t O_PRM  = O_WOUT + 9437184;        // 589,824
    const size_t O_XBF  = O_PRM + 589824;          // 6,291,456
    const size_t O_XF   = O_XBF + 6291456;         // 12,582,912
    const size_t O_XZ   = O_XF + 12582912;         // 50,331,648
    const size_t O_XCBF = O_XZ + 50331648;         // 12,582,912
    const size_t O_DBL  = O_XCBF + 12582912;       // 2,097,152
    const size_t O_DTLR = O_DBL + 2097152;         // 524,288
    const size_t O_DT   = O_DTLR + 524288;         // 25,165,824
    const size_t O_HCH  = O_DT + 25165824;         // 25,165,824 (local h, then prefix h)
    const size_t O_SDT  = O_HCH + 25165824;        // 1,572,864
    const size_t O_YBF  = O_SDT + 1572864;         // 12,582,912

    int* flag = (int*)(ws + O_FLAG);
    unsigned short* Win  = (unsigned short*)(ws + O_WIN);
    unsigned short* Wxp  = (unsigned short*)(ws + O_WXP);
    unsigned short* Wdt  = (unsigned short*)(ws + O_WDT);
    unsigned short* Wout = (unsigned short*)(ws + O_WOUT);
    float* prm = (float*)(ws + O_PRM);
    unsigned short* Xbf = (unsigned short*)(ws + O_XBF);
    float* Xf  = (float*)(ws + O_XF);
    float* Xz  = (float*)(ws + O_XZ);
    unsigned short* Xcbf = (unsigned short*)(ws + O_XCBF);
    float* Dbl = (float*)(ws + O_DBL);
    unsigned short* Dtlr = (unsigned short*)(ws + O_DTLR);
    float* Dt  = (float*)(ws + O_DT);
    float* Hch = (float*)(ws + O_HCH);
    float* Sdt = (float*)(ws + O_SDT);
    unsigned short* Ybf = (unsigned short*)(ws + O_YBF);
    float* Prj = Xz;   // out_proj result reuses xz region (z consumed by then)

    const void* in_x   = d_in[0];
    const void* in_inw = d_in[1];
    const void* in_xpw = d_in[4];
    const void* in_dtw = d_in[5];
    const void* in_ow  = d_in[9];

    k_sniff<<<1, 256, 0, stream>>>((const unsigned short*)in_x, flag);
    k_convx<<<12288, 256, 0, stream>>>(Xbf, Xf, in_x, flag);
    k_conv_bf16<<<36864, 256, 0, stream>>>(Win, in_inw, 9437184L, flag);
    k_conv_bf16<<<18432, 256, 0, stream>>>(Wout, in_ow, 4718592L, flag);
    k_conv_xpw<<<3072, 256, 0, stream>>>(Wxp, in_xpw, flag);
    k_conv_dtw<<<1536, 256, 0, stream>>>(Wdt, in_dtw, flag);
    k_params<<<576, 256, 0, stream>>>(prm, d_in[6], d_in[7], d_in[8], d_in[2], d_in[3],
                                      d_in[10], d_in[11], flag);

    for (int l = 0; l < 4; ++l) {
        const unsigned short* winL  = Win  + (size_t)l * 3072 * 768;
        const unsigned short* wxpL  = Wxp  + (size_t)l * 128 * 1536;
        const unsigned short* wdtL  = Wdt  + (size_t)l * 1536 * 64;
        const unsigned short* woutL = Wout + (size_t)l * 768 * 1536;
        const float* cwL  = prm + OFF_CW  + (size_t)l * DI * 4;
        const float* cbL  = prm + OFF_CB  + (size_t)l * DI;
        const float* dtbL = prm + OFF_DTB + (size_t)l * DI;
        const float* anL  = prm + OFF_A   + (size_t)l * DI * DS;
        const float* dpL  = prm + OFF_DP  + (size_t)l * DI;
        const float* lgL  = prm + OFF_LG  + (size_t)l * DM;
        const float* lbL  = prm + OFF_LB  + (size_t)l * DM;

        // in_proj: [4096,768] x [3072,768]^T -> xz [4096,3072]
        k_gemm128<<<dim3(24, 32), 256, 0, stream>>>(Xbf, winL, Xz, NROWS, 2 * DI, DM);
        // conv + silu -> bf16
        k_conv<<<24576, 256, 0, stream>>>(Xz, cwL, cbL, Xcbf);
        // x_proj: [4096,1536] x [128,1536]^T -> dbl [4096,128]; emit dtlr bf16
        k_gemm64<2><<<dim3(2, 64), 256, 0, stream>>>(Xcbf, wxpL, Dbl, NROWS, 128, DI, nullptr, Dtlr);
        // dt_proj: [4096,64] x [1536,64]^T + bias -> softplus -> dt [4096,1536]
        k_gemm64<1><<<dim3(24, 64), 256, 0, stream>>>(Dtlr, wdtL, Dt, NROWS, DI, 64, dtbL, nullptr);
        // chunked scan
        k_scan1<<<BB * NCH * 6, 256, 0, stream>>>(Dt, Xcbf, Dbl, anL, Hch, Sdt);
        k_scan2<<<192, 256, 0, stream>>>(Hch, Sdt, anL);
        k_scan3<<<BB * NCH * 6, 256, 0, stream>>>(Dt, Xcbf, Dbl, anL, dpL, Hch, Xz, Ybf);
        // out_proj: [4096,1536] x [768,1536]^T -> prj [4096,768]
        k_gemm64<0><<<dim3(12, 64), 256, 0, stream>>>(Ybf, woutL, Prj, NROWS, DM, DI, nullptr, nullptr);
        // layernorm + residual (+ final store on last layer)
        k_ln<<<4096, 256, 0, stream>>>(Prj, Xf, Xbf, lgL, lbL, d_out, (l == 3) ? 1 : 0, flag);
    }
}

// Round 3
// 912.038 us; speedup vs baseline: 1.1634x; 1.1192x over previous
//
#include <hip/hip_runtime.h>

// ---------------- constants ----------------
#define T_LEN 2048
#define DM    768
#define DI    1536
#define DS    16
#define BB    2
#define NROWS (BB * T_LEN)   // 4096
#define NCH   128            // scan chunks per sequence
#define CLEN  16             // chunk length
#define NSEG  8              // segments of 16 chunks each
#define SEGC  16             // chunks per segment

// param-buffer (f32) segment offsets (elements)
#define OFF_DTB 0
#define OFF_A   6144
#define OFF_DP  104448
#define OFF_CW  110592
#define OFF_CB  135168
#define OFF_LG  141312
#define OFF_LB  144384
#define PRM_TOT 147456

typedef __attribute__((ext_vector_type(8))) short bh8;
typedef __attribute__((ext_vector_type(4))) float f32x4;

typedef const __attribute__((address_space(1))) void as1_void;
typedef __attribute__((address_space(3))) void as3_void;

__device__ __forceinline__ void glds16(const void* g, void* l) {
    __builtin_amdgcn_global_load_lds((as1_void*)g, (as3_void*)l, 16, 0, 0);
}

// ---------------- small helpers ----------------
__device__ __forceinline__ float bf2f(unsigned short u) {
    return __uint_as_float(((unsigned)u) << 16);
}
__device__ __forceinline__ unsigned short f2bf(float f) {
    unsigned u = __float_as_uint(f);
    u += 0x7FFFu + ((u >> 16) & 1u);   // RNE
    return (unsigned short)(u >> 16);
}
__device__ __forceinline__ float ldin(const void* p, long i, int bf) {
    return bf ? bf2f(((const unsigned short*)p)[i]) : ((const float*)p)[i];
}

// ---------------- dtype sniffer ----------------
__global__ void k_sniff(const unsigned short* __restrict__ x, int* __restrict__ flag) {
    __shared__ int cnt[4];
    int tid = threadIdx.x;
    int local = 0;
#pragma unroll
    for (int j = 0; j < 4; ++j) {
        unsigned short u = x[tid * 4 + j];
        int e = (u >> 7) & 0xFF;
        if (e >= 100 && e <= 140) local++;
    }
    for (int off = 32; off; off >>= 1) local += __shfl_down(local, off, 64);
    if ((tid & 63) == 0) cnt[tid >> 6] = local;
    __syncthreads();
    if (tid == 0) {
        int tot = cnt[0] + cnt[1] + cnt[2] + cnt[3];
        *flag = (tot >= 900) ? 1 : 0;
    }
}

// ---------------- fused preamble conversion ----------------
// ranges: x | in_proj_w | out_proj_w | x_proj_w(pad) | dt_proj_w(pad) | params
__global__ void k_prep(const void* in_x, const void* in_inw, const void* in_ow,
                       const void* in_xpw, const void* in_dtw,
                       const void* dtb, const void* alog, const void* dpar,
                       const void* cw, const void* cb, const void* lg, const void* lb,
                       unsigned short* __restrict__ xbf, float* __restrict__ xf,
                       unsigned short* __restrict__ Win, unsigned short* __restrict__ Wout,
                       unsigned short* __restrict__ Wxp, unsigned short* __restrict__ Wdt,
                       float* __restrict__ prm, const int* __restrict__ flag) {
    const long E0 = 3145728L;            // x
    const long E1 = E0 + 9437184L;       // in_proj_w
    const long E2 = E1 + 4718592L;       // out_proj_w
    const long E3 = E2 + 786432L;        // x_proj_w padded (4*128*1536)
    const long E4 = E3 + 393216L;        // dt_proj_w padded (4*1536*64)
    const long E5 = E4 + 147456L;        // params
    int bf = *flag;
    long gid = (long)blockIdx.x * 256 + threadIdx.x;
    if (gid < E0) {
        float v = ldin(in_x, gid, bf);
        xbf[gid] = f2bf(v);
        xf[gid]  = v;
    } else if (gid < E1) {
        long i = gid - E0;
        Win[i] = bf ? ((const unsigned short*)in_inw)[i] : f2bf(((const float*)in_inw)[i]);
    } else if (gid < E2) {
        long i = gid - E1;
        Wout[i] = bf ? ((const unsigned short*)in_ow)[i] : f2bf(((const float*)in_ow)[i]);
    } else if (gid < E3) {
        long i = gid - E2;
        int c = (int)(i % 1536);
        long rl = i / 1536;
        int r = (int)(rl % 128);
        int l = (int)(rl / 128);
        unsigned short v = 0;
        if (r < 80) {
            long si = ((long)l * 80 + r) * 1536 + c;
            v = bf ? ((const unsigned short*)in_xpw)[si] : f2bf(((const float*)in_xpw)[si]);
        }
        Wxp[i] = v;
    } else if (gid < E4) {
        long i = gid - E3;
        int c = (int)(i % 64);
        long rl = i / 64;
        int d = (int)(rl % 1536);
        int l = (int)(rl / 1536);
        unsigned short v = 0;
        if (c < 48) {
            long si = ((long)l * 1536 + d) * 48 + c;
            v = bf ? ((const unsigned short*)in_dtw)[si] : f2bf(((const float*)in_dtw)[si]);
        }
        Wdt[i] = v;
    } else if (gid < E5) {
        int i = (int)(gid - E4);
        float v;
        if (i < OFF_A)        v = ldin(dtb, i - OFF_DTB, bf);
        else if (i < OFF_DP)  v = -__expf(ldin(alog, i - OFF_A, bf));
        else if (i < OFF_CW)  v = ldin(dpar, i - OFF_DP, bf);
        else if (i < OFF_CB)  v = ldin(cw, i - OFF_CW, bf);
        else if (i < OFF_LG)  v = ldin(cb, i - OFF_CB, bf);
        else if (i < OFF_LB)  v = ldin(lg, i - OFF_LG, bf);
        else                  v = ldin(lb, i - OFF_LB, bf);
        prm[i] = v;
    }
}

// ---------------- in_proj GEMM: C[M,N]=A@B^T, bf16 in, bf16 out ----------------
__global__ __launch_bounds__(256) void k_gemm128(const unsigned short* __restrict__ A,
                                                 const unsigned short* __restrict__ B,
                                                 unsigned short* __restrict__ C,
                                                 int M, int N, int K) {
    __shared__ __align__(16) unsigned short As[128 * 32];
    __shared__ __align__(16) unsigned short Bs[128 * 32];
    const int tid = threadIdx.x;
    const int lane = tid & 63, wid = tid >> 6;
    const int wm = wid >> 1, wn = wid & 1;
    const long arow0 = (long)blockIdx.y * 128;
    const long bcol0 = (long)blockIdx.x * 128;
    const int r16 = lane >> 2;
    const int c8  = (lane & 3) * 8;
    f32x4 acc[4][4] = {};

    for (int k0 = 0; k0 < K; k0 += 32) {
#pragma unroll
        for (int j = 0; j < 2; ++j) {
            int chunk = wid + j * 4;
            int row = chunk * 16 + r16;
            glds16(&A[(arow0 + row) * K + k0 + c8], &As[chunk * 512]);
            glds16(&B[(bcol0 + row) * K + k0 + c8], &Bs[chunk * 512]);
        }
        __syncthreads();
        const int row = lane & 15, q8 = (lane >> 4) * 8;
        bh8 af[4], bfr[4];
#pragma unroll
        for (int i = 0; i < 4; ++i) af[i] = *(const bh8*)&As[(wm * 64 + i * 16 + row) * 32 + q8];
#pragma unroll
        for (int i = 0; i < 4; ++i) bfr[i] = *(const bh8*)&Bs[(wn * 64 + i * 16 + row) * 32 + q8];
#pragma unroll
        for (int i = 0; i < 4; ++i)
#pragma unroll
            for (int j = 0; j < 4; ++j)
                acc[i][j] = __builtin_amdgcn_mfma_f32_16x16x32_bf16(af[i], bfr[j], acc[i][j], 0, 0, 0);
        __syncthreads();
    }
    const int crow = (lane >> 4) * 4, ccol = lane & 15;
#pragma unroll
    for (int i = 0; i < 4; ++i)
#pragma unroll
        for (int j = 0; j < 4; ++j)
#pragma unroll
            for (int r = 0; r < 4; ++r) {
                long gr = arow0 + wm * 64 + i * 16 + crow + r;
                long gc = bcol0 + wn * 64 + j * 16 + ccol;
                C[gr * N + gc] = f2bf(acc[i][j][r]);
            }
}

// ---------------- x_proj GEMM, split-K with atomic f32 accumulation ----------------
// A = xc bf16 [4096,1536], B = Wxp bf16 [128,1536]; grid (2, 64, 4)
__global__ __launch_bounds__(256) void k_xproj(const unsigned short* __restrict__ A,
                                               const unsigned short* __restrict__ B,
                                               float* __restrict__ C) {
    __shared__ __align__(16) unsigned short As[64 * 32];
    __shared__ __align__(16) unsigned short Bs[64 * 32];
    const int tid = threadIdx.x;
    const int lane = tid & 63, wid = tid >> 6;
    const int wm = wid >> 1, wn = wid & 1;
    const long arow0 = (long)blockIdx.y * 64;
    const long bcol0 = (long)blockIdx.x * 64;
    const int kbase = blockIdx.z * 384;
    const int r16 = lane >> 2;
    const int c8  = (lane & 3) * 8;
    f32x4 acc[2][2] = {};

    for (int kk = 0; kk < 384; kk += 32) {
        int k0 = kbase + kk;
        int row = wid * 16 + r16;
        glds16(&A[(arow0 + row) * DI + k0 + c8], &As[wid * 512]);
        glds16(&B[(bcol0 + row) * DI + k0 + c8], &Bs[wid * 512]);
        __syncthreads();
        const int row2 = lane & 15, q8 = (lane >> 4) * 8;
        bh8 af[2], bfr[2];
#pragma unroll
        for (int i = 0; i < 2; ++i) af[i] = *(const bh8*)&As[(wm * 32 + i * 16 + row2) * 32 + q8];
#pragma unroll
        for (int i = 0; i < 2; ++i) bfr[i] = *(const bh8*)&Bs[(wn * 32 + i * 16 + row2) * 32 + q8];
#pragma unroll
        for (int i = 0; i < 2; ++i)
#pragma unroll
            for (int j = 0; j < 2; ++j)
                acc[i][j] = __builtin_amdgcn_mfma_f32_16x16x32_bf16(af[i], bfr[j], acc[i][j], 0, 0, 0);
        __syncthreads();
    }
    const int crow = (lane >> 4) * 4, ccol = lane & 15;
#pragma unroll
    for (int i = 0; i < 2; ++i)
#pragma unroll
        for (int j = 0; j < 2; ++j)
#pragma unroll
            for (int r = 0; r < 4; ++r) {
                long gr = arow0 + wm * 32 + i * 16 + crow + r;
                long gc = bcol0 + wn * 32 + j * 16 + ccol;
                atomicAdd(&C[gr * 128 + gc], acc[i][j][r]);
            }
}

// ---------------- dt_proj fused: Dbl f32 -> lowrank bf16 (pad) @ Wdt^T + bias -> softplus -> bf16 ----------------
// grid (24, 64); K = 64 (single shot)
__global__ __launch_bounds__(256) void k_dtproj(const float* __restrict__ Dbl,
                                                const unsigned short* __restrict__ Wdt,
                                                const float* __restrict__ bias,
                                                unsigned short* __restrict__ Dt) {
    __shared__ __align__(16) unsigned short As[2 * 64 * 32];  // [panel][row][32]
    __shared__ __align__(16) unsigned short Bs[2 * 64 * 32];
    const int tid = threadIdx.x;
    const int lane = tid & 63, wid = tid >> 6;
    const int wm = wid >> 1, wn = wid & 1;
    const long arow0 = (long)blockIdx.y * 64;
    const long bcol0 = (long)blockIdx.x * 64;

    // stage A: 64 rows x 64 cols (cols 48..63 zero), f32 -> bf16
    {
        int r = tid >> 2;
        int cs = (tid & 3) * 16;
        unsigned short tmp[16];
#pragma unroll
        for (int q = 0; q < 4; ++q) {
            int col0 = cs + q * 4;
            if (col0 < 48) {
                f32x4 v = *(const f32x4*)&Dbl[(arow0 + r) * 128 + col0];
#pragma unroll
                for (int j = 0; j < 4; ++j) tmp[q * 4 + j] = f2bf(v[j]);
            } else {
#pragma unroll
                for (int j = 0; j < 4; ++j) tmp[q * 4 + j] = 0;
            }
        }
        int p = cs >> 5;              // panel (cs: 0,16 -> 0 ; 32,48 -> 1)
        int cp = cs & 31;
        *(bh8*)&As[p * 2048 + r * 32 + cp]     = *(bh8*)&tmp[0];
        *(bh8*)&As[p * 2048 + r * 32 + cp + 8] = *(bh8*)&tmp[8];
    }
    // stage B via glds: Wdt [64 rows][64 k] -> Bs [panel][row][32]
#pragma unroll
    for (int j = 0; j < 2; ++j) {
        int chunk = tid + j * 256;        // 0..511
        int p = chunk >> 8;
        int rem = chunk & 255;
        int row = rem >> 2;
        int c4 = rem & 3;
        glds16(&Wdt[(bcol0 + row) * 64 + p * 32 + c4 * 8], &Bs[chunk * 8]);
    }
    __syncthreads();

    const int row2 = lane & 15, q8 = (lane >> 4) * 8;
    f32x4 acc[2][2] = {};
#pragma unroll
    for (int p = 0; p < 2; ++p) {
        bh8 af[2], bfr[2];
#pragma unroll
        for (int i = 0; i < 2; ++i) af[i] = *(const bh8*)&As[p * 2048 + (wm * 32 + i * 16 + row2) * 32 + q8];
#pragma unroll
        for (int i = 0; i < 2; ++i) bfr[i] = *(const bh8*)&Bs[p * 2048 + (wn * 32 + i * 16 + row2) * 32 + q8];
#pragma unroll
        for (int i = 0; i < 2; ++i)
#pragma unroll
            for (int j = 0; j < 2; ++j)
                acc[i][j] = __builtin_amdgcn_mfma_f32_16x16x32_bf16(af[i], bfr[j], acc[i][j], 0, 0, 0);
    }
    const int crow = (lane >> 4) * 4, ccol = lane & 15;
#pragma unroll
    for (int i = 0; i < 2; ++i)
#pragma unroll
        for (int j = 0; j < 2; ++j)
#pragma unroll
            for (int r = 0; r < 4; ++r) {
                long gr = arow0 + wm * 32 + i * 16 + crow + r;
                long gc = bcol0 + wn * 32 + j * 16 + ccol;
                float v = acc[i][j][r] + bias[gc];
                v = (v > 20.f) ? v : log1pf(__expf(v));
                Dt[gr * DI + gc] = f2bf(v);
            }
}

// ---------------- out_proj GEMM: bf16 in, f32 out ----------------
__global__ __launch_bounds__(256) void k_outproj(const unsigned short* __restrict__ A,
                                                 const unsigned short* __restrict__ B,
                                                 float* __restrict__ C) {
    __shared__ __align__(16) unsigned short As[64 * 32];
    __shared__ __align__(16) unsigned short Bs[64 * 32];
    const int tid = threadIdx.x;
    const int lane = tid & 63, wid = tid >> 6;
    const int wm = wid >> 1, wn = wid & 1;
    const long arow0 = (long)blockIdx.y * 64;
    const long bcol0 = (long)blockIdx.x * 64;
    const int r16 = lane >> 2;
    const int c8  = (lane & 3) * 8;
    f32x4 acc[2][2] = {};

    for (int k0 = 0; k0 < DI; k0 += 32) {
        int row = wid * 16 + r16;
        glds16(&A[(arow0 + row) * DI + k0 + c8], &As[wid * 512]);
        glds16(&B[(bcol0 + row) * DI + k0 + c8], &Bs[wid * 512]);
        __syncthreads();
        const int row2 = lane & 15, q8 = (lane >> 4) * 8;
        bh8 af[2], bfr[2];
#pragma unroll
        for (int i = 0; i < 2; ++i) af[i] = *(const bh8*)&As[(wm * 32 + i * 16 + row2) * 32 + q8];
#pragma unroll
        for (int i = 0; i < 2; ++i) bfr[i] = *(const bh8*)&Bs[(wn * 32 + i * 16 + row2) * 32 + q8];
#pragma unroll
        for (int i = 0; i < 2; ++i)
#pragma unroll
            for (int j = 0; j < 2; ++j)
                acc[i][j] = __builtin_amdgcn_mfma_f32_16x16x32_bf16(af[i], bfr[j], acc[i][j], 0, 0, 0);
        __syncthreads();
    }
    const int crow = (lane >> 4) * 4, ccol = lane & 15;
#pragma unroll
    for (int i = 0; i < 2; ++i)
#pragma unroll
        for (int j = 0; j < 2; ++j)
#pragma unroll
            for (int r = 0; r < 4; ++r) {
                long gr = arow0 + wm * 32 + i * 16 + crow + r;
                long gc = bcol0 + wn * 32 + j * 16 + ccol;
                C[gr * DM + gc] = acc[i][j][r];
            }
}

// ---------------- tiled depthwise causal conv + SiLU (bf16 in/out) ----------------
// grid (24 d-tiles, 32 bt-tiles of 128)
__global__ __launch_bounds__(256) void k_conv(const unsigned short* __restrict__ xz,
                                              const float* __restrict__ cw,
                                              const float* __restrict__ cb,
                                              unsigned short* __restrict__ xcbf) {
    __shared__ float tile[131 * 64];
    const int tid = threadIdx.x;
    const int d0 = blockIdx.x * 64;
    const long t0 = (long)blockIdx.y * 128;
    const bool seqstart = ((int)t0 & (T_LEN - 1)) == 0;
    for (int j = tid; j < 131 * 64; j += 256) {
        int row = j >> 6, col = j & 63;
        float v = 0.f;
        if (!(seqstart && row < 3)) v = bf2f(xz[(t0 - 3 + row) * (2 * DI) + d0 + col]);
        tile[j] = v;
    }
    __syncthreads();
    const int d = tid & 63, tl0 = tid >> 6;
    const int dg = d0 + d;
    const float w0 = cw[dg * 4 + 0], w1 = cw[dg * 4 + 1];
    const float w2 = cw[dg * 4 + 2], w3 = cw[dg * 4 + 3];
    const float bias = cb[dg];
    for (int tt = tl0; tt < 128; tt += 4) {
        float acc = bias + w0 * tile[tt * 64 + d] + w1 * tile[(tt + 1) * 64 + d]
                         + w2 * tile[(tt + 2) * 64 + d] + w3 * tile[(tt + 3) * 64 + d];
        float s = acc / (1.f + __expf(-acc));
        xcbf[(t0 + tt) * DI + dg] = f2bf(s);
    }
}

// ---------------- chunked selective scan ----------------
// phase 1: per (b,chunk,d): local scan from h=0; store final h and sum(dt)
__global__ __launch_bounds__(256) void k_scan1(const unsigned short* __restrict__ dt,
                                               const unsigned short* __restrict__ xcbf,
                                               const float* __restrict__ dbl,
                                               const float* __restrict__ An,
                                               float* __restrict__ hch,
                                               float* __restrict__ sdtb) {
    const int tid = threadIdx.x;
    const int db = blockIdx.x % 6;
    const int c  = (blockIdx.x / 6) % NCH;
    const int b  = blockIdx.x / (6 * NCH);
    const int d  = db * 256 + tid;
    const int t0 = c * CLEN;
    float h[DS], An_r[DS];
    const f32x4* Ap = (const f32x4*)(An + (long)d * DS);
#pragma unroll
    for (int q = 0; q < 4; ++q) {
        f32x4 a4 = Ap[q];
#pragma unroll
        for (int j = 0; j < 4; ++j) { An_r[q * 4 + j] = a4[j]; h[q * 4 + j] = 0.f; }
    }
    float sdt = 0.f;
    const long rowb = (long)b * T_LEN + t0;
#pragma unroll 4
    for (int s = 0; s < CLEN; ++s) {
        long bt = rowb + s;
        float dtv = bf2f(dt[bt * DI + d]);
        float xcv = bf2f(xcbf[bt * DI + d]);
        int bi = __builtin_amdgcn_readfirstlane((int)(bt * 128 + 48));
        const f32x4* bp = (const f32x4*)(dbl + bi);
        float Bv[DS];
#pragma unroll
        for (int q = 0; q < 4; ++q) {
            f32x4 b4 = bp[q];
#pragma unroll
            for (int j = 0; j < 4; ++j) Bv[q * 4 + j] = b4[j];
        }
        float du = dtv * xcv;
        sdt += dtv;
#pragma unroll
        for (int n = 0; n < DS; ++n)
            h[n] = __expf(An_r[n] * dtv) * h[n] + du * Bv[n];
    }
    long o = (((long)b * NCH + c) * DI + d) * DS;
    f32x4* hp = (f32x4*)(hch + o);
#pragma unroll
    for (int q = 0; q < 4; ++q) {
        f32x4 h4;
#pragma unroll
        for (int j = 0; j < 4; ++j) h4[j] = h[q * 4 + j];
        hp[q] = h4;
    }
    sdtb[((long)b * NCH + c) * DI + d] = sdt;
}

// phase 2a: per (b,seg,d,n): within-segment combine over 16 chunks.
// hbuf: in = local h per chunk; out = within-segment prefix h (before chunk).
// also writes per-chunk cumulative dt (n==0 lanes) and segment aggregates G,S.
__global__ __launch_bounds__(256) void k_scan2a(float* __restrict__ hbuf,
                                                const float* __restrict__ sdtb,
                                                const float* __restrict__ An,
                                                float* __restrict__ cum,
                                                float* __restrict__ Gseg,
                                                float* __restrict__ Sseg) {
    long gid = (long)blockIdx.x * 256 + threadIdx.x;
    int n = (int)(gid & 15);
    long t = gid >> 4;
    int d  = (int)(t % DI);
    int sg = (int)((t / DI) & (NSEG - 1));
    int b  = (int)(t / (DI * NSEG));
    float an = An[(long)d * DS + n];
    float h = 0.f, cs = 0.f;
    for (int i = 0; i < SEGC; ++i) {
        int c = sg * SEGC + i;
        long rowi = ((long)b * NCH + c) * DI + d;
        long idx = rowi * DS + n;
        float sdt = sdtb[rowi];
        float g = hbuf[idx];
        hbuf[idx] = h;
        if (n == 0) cum[rowi] = cs;
        h = __expf(an * sdt) * h + g;
        cs += sdt;
    }
    long gi = (((long)b * NSEG + sg) * DI + d) * DS + n;
    Gseg[gi] = h;
    if (n == 0) Sseg[((long)b * NSEG + sg) * DI + d] = cs;
}

// phase 2b: per (b,d,n): combine 8 segments; Hseg = incoming h at segment start.
__global__ __launch_bounds__(256) void k_scan2b(const float* __restrict__ Gseg,
                                                const float* __restrict__ Sseg,
                                                const float* __restrict__ An,
                                                float* __restrict__ Hseg) {
    long gid = (long)blockIdx.x * 256 + threadIdx.x;
    int n = (int)(gid & 15);
    long t = gid >> 4;
    int d = (int)(t % DI);
    int b = (int)(t / DI);
    float an = An[(long)d * DS + n];
    float H = 0.f;
    for (int sg = 0; sg < NSEG; ++sg) {
        long gi = (((long)b * NSEG + sg) * DI + d) * DS + n;
        float G = Gseg[gi];
        float S = Sseg[((long)b * NSEG + sg) * DI + d];
        Hseg[gi] = H;
        H = __expf(an * S) * H + G;
    }
}

// phase 3: h0 = exp(an*cum)*Hseg + within-seg prefix; rescan; gate; emit bf16
__global__ __launch_bounds__(256) void k_scan3(const unsigned short* __restrict__ dt,
                                               const unsigned short* __restrict__ xcbf,
                                               const float* __restrict__ dbl,
                                               const float* __restrict__ An,
                                               const float* __restrict__ Dp,
                                               const float* __restrict__ hpref,
                                               const float* __restrict__ cum,
                                               const float* __restrict__ Hseg,
                                               const unsigned short* __restrict__ xz,
                                               unsigned short* __restrict__ ybf) {
    const int tid = threadIdx.x;
    const int db = blockIdx.x % 6;
    const int c  = (blockIdx.x / 6) % NCH;
    const int b  = blockIdx.x / (6 * NCH);
    const int d  = db * 256 + tid;
    const int t0 = c * CLEN;
    const int sg = c / SEGC;
    float h[DS], An_r[DS];
    long rowi = ((long)b * NCH + c) * DI + d;
    long o = rowi * DS;
    long gi = (((long)b * NSEG + sg) * DI + d) * DS;
    const float cs = cum[rowi];
    const f32x4* Ap = (const f32x4*)(An + (long)d * DS);
    const f32x4* Pp = (const f32x4*)(hpref + o);
    const f32x4* Hp = (const f32x4*)(Hseg + gi);
#pragma unroll
    for (int q = 0; q < 4; ++q) {
        f32x4 a4 = Ap[q], p4 = Pp[q], h4 = Hp[q];
#pragma unroll
        for (int j = 0; j < 4; ++j) {
            int n = q * 4 + j;
            An_r[n] = a4[j];
            h[n] = __expf(a4[j] * cs) * h4[j] + p4[j];
        }
    }
    const float dcoef = Dp[d];
    const long rowb = (long)b * T_LEN + t0;
#pragma unroll 4
    for (int s = 0; s < CLEN; ++s) {
        long bt = rowb + s;
        float dtv = bf2f(dt[bt * DI + d]);
        float xcv = bf2f(xcbf[bt * DI + d]);
        int bi = __builtin_amdgcn_readfirstlane((int)(bt * 128 + 48));
        const f32x4* bp = (const f32x4*)(dbl + bi);
        float Bv[DS], Cv[DS];
#pragma unroll
        for (int q = 0; q < 4; ++q) {
            f32x4 b4 = bp[q], c4 = bp[q + 4];
#pragma unroll
            for (int j = 0; j < 4; ++j) { Bv[q * 4 + j] = b4[j]; Cv[q * 4 + j] = c4[j]; }
        }
        float du = dtv * xcv;
        float yp[4] = {xcv * dcoef, 0.f, 0.f, 0.f};
#pragma unroll
        for (int n = 0; n < DS; ++n) {
            h[n] = __expf(An_r[n] * dtv) * h[n] + du * Bv[n];
            yp[n & 3] += h[n] * Cv[n];
        }
        float y = (yp[0] + yp[1]) + (yp[2] + yp[3]);
        float zv = bf2f(xz[bt * (2 * DI) + DI + d]);
        y *= zv / (1.f + __expf(-zv));
        ybf[bt * DI + d] = f2bf(y);
    }
}

// ---------------- LayerNorm + residual (+ final output store) ----------------
__global__ __launch_bounds__(256) void k_ln(const float* __restrict__ prj,
                                            float* __restrict__ x,
                                            unsigned short* __restrict__ xbf,
                                            const float* __restrict__ lg,
                                            const float* __restrict__ lb,
                                            void* __restrict__ dout,
                                            int is_last, const int* __restrict__ flag) {
    __shared__ float red[8];
    const int row = blockIdx.x;
    const int tid = threadIdx.x;
    float v[3];
    float s = 0.f, s2 = 0.f;
#pragma unroll
    for (int j = 0; j < 3; ++j) {
        v[j] = prj[(long)row * DM + tid + j * 256];
        s += v[j];
        s2 += v[j] * v[j];
    }
    for (int off = 32; off; off >>= 1) {
        s  += __shfl_down(s, off, 64);
        s2 += __shfl_down(s2, off, 64);
    }
    if ((tid & 63) == 0) { red[tid >> 6] = s; red[4 + (tid >> 6)] = s2; }
    __syncthreads();
    float S  = red[0] + red[1] + red[2] + red[3];
    float S2 = red[4] + red[5] + red[6] + red[7];
    float mu = S * (1.f / DM);
    float var = S2 * (1.f / DM) - mu * mu;
    float rs = rsqrtf(var + 1e-5f);
    int bf = *flag;
#pragma unroll
    for (int j = 0; j < 3; ++j) {
        int e = tid + j * 256;
        long idx = (long)row * DM + e;
        float out = (v[j] - mu) * rs * lg[e] + lb[e] + x[idx];
        x[idx] = out;
        xbf[idx] = f2bf(out);
        if (is_last) {
            if (bf) ((unsigned short*)dout)[idx] = f2bf(out);
            else    ((float*)dout)[idx] = out;
        }
    }
}

// ---------------- host launcher ----------------
extern "C" void kernel_launch(void* const* d_in, const int* in_sizes, int n_in,
                              void* d_out, int out_size, void* d_ws, size_t ws_size,
                              hipStream_t stream) {
    char* ws = (char*)d_ws;
    const size_t O_FLAG = 0;
    const size_t O_WIN  = 256;
    const size_t O_WXP  = O_WIN  + 18874368;
    const size_t O_WDT  = O_WXP  + 1572864;
    const size_t O_WOUT = O_WDT  + 786432;
    const size_t O_PRM  = O_WOUT + 9437184;
    const size_t O_XBF  = O_PRM  + 589824;
    const size_t O_XF   = O_XBF  + 6291456;
    const size_t O_XZ   = O_XF   + 12582912;   // bf16 [4096,3072]; f32 Prj aliases
    const size_t O_XCBF = O_XZ   + 25165824;
    const size_t O_DBL  = O_XCBF + 12582912;
    const size_t O_DT   = O_DBL  + 2097152;    // bf16
    const size_t O_HCH  = O_DT   + 12582912;
    const size_t O_SDT  = O_HCH  + 25165824;
    const size_t O_CUM  = O_SDT  + 1572864;
    const size_t O_GSEG = O_CUM  + 1572864;
    const size_t O_SSEG = O_GSEG + 1572864;
    const size_t O_HSEG = O_SSEG + 98304;
    const size_t O_YBF  = O_HSEG + 1572864;

    int* flag = (int*)(ws + O_FLAG);
    unsigned short* Win  = (unsigned short*)(ws + O_WIN);
    unsigned short* Wxp  = (unsigned short*)(ws + O_WXP);
    unsigned short* Wdt  = (unsigned short*)(ws + O_WDT);
    unsigned short* Wout = (unsigned short*)(ws + O_WOUT);
    float* prm = (float*)(ws + O_PRM);
    unsigned short* Xbf = (unsigned short*)(ws + O_XBF);
    float* Xf  = (float*)(ws + O_XF);
    unsigned short* Xz = (unsigned short*)(ws + O_XZ);
    unsigned short* Xcbf = (unsigned short*)(ws + O_XCBF);
    float* Dbl = (float*)(ws + O_DBL);
    unsigned short* Dt = (unsigned short*)(ws + O_DT);
    float* Hch = (float*)(ws + O_HCH);
    float* Sdt = (float*)(ws + O_SDT);
    float* Cum = (float*)(ws + O_CUM);
    float* Gsg = (float*)(ws + O_GSEG);
    float* Ssg = (float*)(ws + O_SSEG);
    float* Hsg = (float*)(ws + O_HSEG);
    unsigned short* Ybf = (unsigned short*)(ws + O_YBF);
    float* Prj = (float*)(ws + O_XZ);   // alias: z consumed by scan3 before out_proj writes

    k_sniff<<<1, 256, 0, stream>>>((const unsigned short*)d_in[0], flag);
    k_prep<<<72768, 256, 0, stream>>>(d_in[0], d_in[1], d_in[9], d_in[4], d_in[5],
                                      d_in[6], d_in[7], d_in[8], d_in[2], d_in[3],
                                      d_in[10], d_in[11],
                                      Xbf, Xf, Win, Wout, Wxp, Wdt, prm, flag);

    for (int l = 0; l < 4; ++l) {
        const unsigned short* winL  = Win  + (size_t)l * 3072 * 768;
        const unsigned short* wxpL  = Wxp  + (size_t)l * 128 * 1536;
        const unsigned short* wdtL  = Wdt  + (size_t)l * 1536 * 64;
        const unsigned short* woutL = Wout + (size_t)l * 768 * 1536;
        const float* cwL  = prm + OFF_CW  + (size_t)l * DI * 4;
        const float* cbL  = prm + OFF_CB  + (size_t)l * DI;
        const float* dtbL = prm + OFF_DTB + (size_t)l * DI;
        const float* anL  = prm + OFF_A   + (size_t)l * DI * DS;
        const float* dpL  = prm + OFF_DP  + (size_t)l * DI;
        const float* lgL  = prm + OFF_LG  + (size_t)l * DM;
        const float* lbL  = prm + OFF_LB  + (size_t)l * DM;

        k_gemm128<<<dim3(24, 32), 256, 0, stream>>>(Xbf, winL, Xz, NROWS, 2 * DI, DM);
        k_conv<<<dim3(24, 32), 256, 0, stream>>>(Xz, cwL, cbL, Xcbf);
        hipMemsetAsync(Dbl, 0, 2097152, stream);
        k_xproj<<<dim3(2, 64, 4), 256, 0, stream>>>(Xcbf, wxpL, Dbl);
        k_dtproj<<<dim3(24, 64), 256, 0, stream>>>(Dbl, wdtL, dtbL, Dt);
        k_scan1<<<BB * NCH * 6, 256, 0, stream>>>(Dt, Xcbf, Dbl, anL, Hch, Sdt);
        k_scan2a<<<1536, 256, 0, stream>>>(Hch, Sdt, anL, Cum, Gsg, Ssg);
        k_scan2b<<<192, 256, 0, stream>>>(Gsg, Ssg, anL, Hsg);
        k_scan3<<<BB * NCH * 6, 256, 0, stream>>>(Dt, Xcbf, Dbl, anL, dpL, Hch, Cum, Hsg, Xz, Ybf);
        k_outproj<<<dim3(12, 64), 256, 0, stream>>>(Ybf, woutL, Prj);
        k_ln<<<4096, 256, 0, stream>>>(Prj, Xf, Xbf, lgL, lbL, d_out, (l == 3) ? 1 : 0, flag);
    }
}